// Round 4
// baseline (530.247 us; speedup 1.0000x reference)
//
#include <hip/hip_runtime.h>
#include <hip/hip_bf16.h>

typedef __bf16 bf16;
typedef __bf16 bf16x2 __attribute__((ext_vector_type(2)));
typedef __bf16 bf16x8 __attribute__((ext_vector_type(8)));
typedef float floatx4 __attribute__((ext_vector_type(4)));

#define NB_ 8192
#define NU_ 32768

__device__ __forceinline__ float silu_f(float x) {
    float e = __expf(-x);
    return x * __builtin_amdgcn_rcpf(1.0f + e);
}

__device__ __forceinline__ float2 unpack_bf2(unsigned v) {
    float2 r;
    r.x = __uint_as_float(v << 16);
    r.y = __uint_as_float(v & 0xFFFF0000u);
    return r;
}

// async global -> LDS, 16B per lane; lds dest = wave-uniform base + lane*16 (HW rule)
__device__ __forceinline__ void gll16(const bf16* g, bf16* l) {
    __builtin_amdgcn_global_load_lds((const __attribute__((address_space(1))) void*)g,
                                     (__attribute__((address_space(3))) void*)l, 16, 0, 0);
}

// =================== init: setup + weight transpose + ebias + zeroing ===================
__global__ __launch_bounds__(256) void init_kernel(
    const float* __restrict__ Z, const float* __restrict__ noise,
    const int* __restrict__ nl, const float* __restrict__ sig,
    const int* __restrict__ Aarr, const int* __restrict__ posa, const int* __restrict__ Barr,
    const float* __restrict__ atom_emb, const float* __restrict__ pos_emb,
    const float* __restrict__ block_emb,
    const float* __restrict__ edge_emb, const float* __restrict__ We,
    const float* __restrict__ Wm, const float* __restrict__ Wu, const float* __restrict__ W1,
    float* __restrict__ Zp, float* __restrict__ Zb0, float* __restrict__ Zb,
    float* __restrict__ hf, bf16* __restrict__ hb,
    bf16* __restrict__ WmT, bf16* __restrict__ WuT, bf16* __restrict__ W1T,
    float* __restrict__ ebias,
    float* __restrict__ out_gr, float* __restrict__ out_e, float* __restrict__ out_loss)
{
    __shared__ float zsh[12];
    __shared__ float tile[32][33];
    int bid = blockIdx.x, tid = threadIdx.x;
    if (bid < 8192) {
        int b = bid, g = b >> 10;
        if (tid < 12) {
            float sg = sig[nl[g]];
            int idx = b*12 + tid;
            float zp = Z[idx] + noise[idx]*sg;
            Zp[idx] = zp;
            zsh[tid] = zp;
        }
        __syncthreads();
        if (tid < 3) {
            float v = 0.25f*(zsh[tid] + zsh[3+tid] + zsh[6+tid] + zsh[9+tid]);
            Zb0[b*3+tid] = v; Zb[b*3+tid] = v;
        }
        int ai[4], pi[4];
        #pragma unroll
        for (int a = 0; a < 4; a++) { ai[a] = Aarr[b*4+a]*512; pi[a] = posa[b*4+a]*512; }
        int bb = Barr[b]*512;
        int c0 = tid*2;
        float sx = 0.0f, sy = 0.0f;
        #pragma unroll
        for (int a = 0; a < 4; a++) {
            float2 va = *(const float2*)(atom_emb + ai[a] + c0);
            float2 vp = *(const float2*)(pos_emb + pi[a] + c0);
            sx += va.x + vp.x; sy += va.y + vp.y;
        }
        float2 vb = *(const float2*)(block_emb + bb + c0);
        sx = 0.25f*sx + vb.x; sy = 0.25f*sy + vb.y;
        *(float2*)(hf + (size_t)b*512 + c0) = make_float2(sx, sy);
        bf16x2 hp = { (bf16)sx, (bf16)sy };
        *(bf16x2*)(hb + (size_t)b*512 + c0) = hp;
        return;
    }
    bid -= 8192;
    if (bid < 1792) {   // 7 matrices x 256 tiles (16x16 of 32x32)
        int z = bid >> 8, rem = bid & 255;
        int bx = rem & 15, by = rem >> 4;
        int tx = tid & 31, ty = tid >> 5;     // 32 x 8
        const float* src; bf16* dst;
        if (z < 3)      { src = Wm + (size_t)z*262144;     dst = WmT + (size_t)z*262144; }
        else if (z < 6) { src = Wu + (size_t)(z-3)*262144; dst = WuT + (size_t)(z-3)*262144; }
        else            { src = W1;                        dst = W1T; }
        #pragma unroll
        for (int i = 0; i < 32; i += 8)
            tile[ty+i][tx] = src[(size_t)(by*32+ty+i)*512 + bx*32+tx];
        __syncthreads();
        #pragma unroll
        for (int i = 0; i < 32; i += 8)
            dst[(size_t)(bx*32+ty+i)*512 + by*32+tx] = (bf16)tile[tx][ty+i];
        return;
    }
    bid -= 1792;
    if (bid < 12) {
        int gid = bid*256 + tid;
        int l = gid >> 10, t = (gid >> 9) & 1, c = gid & 511;
        float s = 0.0f;
        #pragma unroll 8
        for (int e = 0; e < 64; e++)
            s += edge_emb[t*64 + e] * We[(size_t)(l*64 + e)*512 + c];
        ebias[gid] = s;
        return;
    }
    bid -= 12;
    int k = bid*256 + tid;
    if (k < 4096) out_gr[k] = 0.0f;
    else if (k < 4104) out_e[k-4096] = 0.0f;
    else if (k == 4104) out_loss[0] = 0.0f;
}

// =================== KNN: one WG per dst block; 4 waves split the 1024-src scan ===================
// u32 keys: (distbits & ~1023) | j  -> argmin via v_min_u32; unique keys -> winner by equality
__device__ void knn_body(int kb, const float* __restrict__ Zp, const int* __restrict__ seg,
                         int* __restrict__ nbr, unsigned* __restrict__ l1) {
    int tid = threadIdx.x, w = tid >> 6, lane = tid & 63;
    int g = kb & 7, rl = kb >> 3;                 // XCD-local graph
    int r = (g << 10) + rl;
    int base = g << 10;
    int segr = seg[r];
    const float4* zp4 = (const float4*)(Zp + (size_t)r*12);
    float4 a0 = zp4[0], a1 = zp4[1], a2 = zp4[2];
    float ax[4] = {a0.x, a0.w, a1.z, a2.y};
    float ay[4] = {a0.y, a1.x, a1.w, a2.z};
    float az[4] = {a0.z, a1.y, a2.x, a2.w};
    unsigned kin[4], kout[4];
    #pragma unroll
    for (int t = 0; t < 4; t++) {
        int j = w*256 + t*64 + lane;
        int jb = base + j;
        const float4* p = (const float4*)(Zp + (size_t)jb*12);
        float4 v0 = p[0], v1 = p[1], v2 = p[2];
        float bx[4] = {v0.x, v0.w, v1.z, v2.y};
        float by[4] = {v0.y, v1.x, v1.w, v2.z};
        float bz[4] = {v0.z, v1.y, v2.x, v2.w};
        float dm = 3.0e38f;
        #pragma unroll
        for (int a = 0; a < 4; a++) {
            #pragma unroll
            for (int bq = 0; bq < 4; bq++) {
                float dx = ax[a]-bx[bq], dy = ay[a]-by[bq], dz = az[a]-bz[bq];
                dm = fminf(dm, dx*dx + dy*dy + dz*dz);
            }
        }
        unsigned kd = (__float_as_uint(dm) & 0xFFFFFC00u) | (unsigned)j;
        bool same = (seg[jb] == segr);
        kin[t]  = (same && j != rl) ? kd : 0xFFFFFFFFu;
        kout[t] = (!same)           ? kd : 0xFFFFFFFFu;
    }
    if (tid < 128) l1[tid] = 0xFFFFFFFFu;
    __syncthreads();
    #pragma unroll
    for (int ph = 0; ph < 2; ph++) {
        unsigned wd[4];
        #pragma unroll
        for (int t = 0; t < 4; t++) wd[t] = ph ? kout[t] : kin[t];
        for (int it = 0; it < 9; it++) {
            unsigned bk = min(min(wd[0], wd[1]), min(wd[2], wd[3]));
            unsigned mv = bk;
            #pragma unroll
            for (int off = 32; off >= 1; off >>= 1)
                mv = min(mv, (unsigned)__shfl_xor((int)mv, off, 64));
            if (lane == 0) l1[ph*64 + w*16 + it] = mv;
            if (bk == mv) {
                #pragma unroll
                for (int t = 0; t < 4; t++) if (wd[t] == mv) wd[t] = 0xFFFFFFFFu;
            }
        }
    }
    __syncthreads();
    if (w < 2) {
        int ph = w;
        int w2 = lane >> 4, it2 = lane & 15;
        unsigned key = (it2 < 9) ? l1[ph*64 + w2*16 + it2] : 0xFFFFFFFFu;
        for (int it = 0; it < 9; it++) {
            unsigned mv = key;
            #pragma unroll
            for (int off = 32; off >= 1; off >>= 1)
                mv = min(mv, (unsigned)__shfl_xor((int)mv, off, 64));
            if (key == mv) key = 0xFFFFFFFFu;
            if (lane == 0) nbr[r*18 + ph*9 + it] = base + (int)(mv & 1023u);
        }
    }
}

// =================== bf16 MFMA GEMM body: 64x64 tile, BK=32, double-buffered LDS ===================
// grid 1024 (128 M-tiles x 8 N-tiles) -> 4 WG/CU
// mode 0: Pb = bf16(acc)
// mode 1: hf += silu(acc); hb = bf16(hf); if shp: shp = bf16(silu(hf)); nt==0 also folds Zb += zacc/18
// mode 2: s = silu(acc + b1)·W2, wave-reduced, atomicAdd to out_e[graph]
__device__ void gemm_body(const bf16* __restrict__ A, const bf16* __restrict__ BT,
                          bf16* __restrict__ Pb, float* __restrict__ hf,
                          bf16* __restrict__ hb, bf16* __restrict__ shp,
                          const float* __restrict__ b1, const float* __restrict__ W2,
                          float* __restrict__ out_e,
                          float* __restrict__ Zb, const float* __restrict__ zacc,
                          int mode, int bid, bf16* __restrict__ sA, bf16* __restrict__ sB)
{
    int mt = bid & 127, nt = bid >> 7;
    int m0 = mt*64, n0 = nt*64;
    int tid = threadIdx.x, lane = tid & 63, w = tid >> 6;
    int wm = w & 1, wn = w >> 1;
    int lm = lane & 15, q = lane >> 4;

    // staging: physical chunk tid holds logical (row=tid>>2, qt=(tid&3)^((row>>1)&3))
    int row = tid >> 2;
    int qt = (tid & 3) ^ ((row >> 1) & 3);
    const bf16* gA = A  + (size_t)(m0 + row)*512 + qt*8;
    const bf16* gB = BT + (size_t)(n0 + row)*512 + qt*8;
    bf16* lA = sA + tid*8 - lane*8;   // wave-uniform base (HW adds lane*16B)
    bf16* lB = sB + tid*8 - lane*8;
    int swq = (q ^ ((lm >> 1) & 3)) * 8;

    floatx4 zv = {0.0f, 0.0f, 0.0f, 0.0f};
    floatx4 acc[2][2];
    #pragma unroll
    for (int i = 0; i < 2; i++)
        #pragma unroll
        for (int j = 0; j < 2; j++) acc[i][j] = zv;

    gll16(gA, lA);
    gll16(gB, lB);
    for (int k = 0; k < 16; k++) {
        int cur = (k & 1)*2048;
        __syncthreads();
        if (k < 15) {
            int nxt = ((k+1) & 1)*2048;
            gll16(gA + (k+1)*32, lA + nxt);
            gll16(gB + (k+1)*32, lB + nxt);
        }
        const bf16* bA = sA + cur;
        const bf16* bB = sB + cur;
        bf16x8 af[2], bfr[2];
        af[0]  = *(const bf16x8*)(bA + (wm*32      + lm)*32 + swq);
        af[1]  = *(const bf16x8*)(bA + (wm*32 + 16 + lm)*32 + swq);
        bfr[0] = *(const bf16x8*)(bB + (wn*32      + lm)*32 + swq);
        bfr[1] = *(const bf16x8*)(bB + (wn*32 + 16 + lm)*32 + swq);
        #pragma unroll
        for (int tm = 0; tm < 2; tm++)
            #pragma unroll
            for (int tn = 0; tn < 2; tn++)
                acc[tm][tn] = __builtin_amdgcn_mfma_f32_16x16x32_bf16(af[tm], bfr[tn], acc[tm][tn], 0, 0, 0);
    }

    if (mode == 2) {
        float s = 0.0f;
        #pragma unroll
        for (int tn = 0; tn < 2; tn++) {
            int col = n0 + wn*32 + tn*16 + lm;
            float bb = b1[col], ww = W2[col];
            #pragma unroll
            for (int tm = 0; tm < 2; tm++)
                #pragma unroll
                for (int rr = 0; rr < 4; rr++)
                    s += silu_f(acc[tm][tn][rr] + bb) * ww;
        }
        #pragma unroll
        for (int off = 32; off >= 1; off >>= 1) s += __shfl_xor(s, off, 64);
        if (lane == 0) atomicAdd(&out_e[m0 >> 10], s);
        return;
    }
    if (mode == 1 && nt == 0 && tid < 192) {   // fold zb_apply for rows m0..m0+63
        int o = m0*3 + tid;
        Zb[o] += zacc[o] * (1.0f/18.0f);
    }
    #pragma unroll
    for (int tm = 0; tm < 2; tm++) {
        #pragma unroll
        for (int tn = 0; tn < 2; tn++) {
            #pragma unroll
            for (int rr = 0; rr < 4; rr++) {
                int r2 = m0 + wm*32 + tm*16 + q*4 + rr;
                int c2 = n0 + wn*32 + tn*16 + lm;
                size_t o = (size_t)r2*512 + c2;
                float v = acc[tm][tn][rr];
                if (mode == 0) {
                    Pb[o] = (bf16)v;
                } else {
                    float nh = hf[o] + silu_f(v);
                    hf[o] = nh;
                    hb[o] = (bf16)nh;
                    if (shp) shp[o] = (bf16)silu_f(nh);
                }
            }
        }
    }
}

__global__ __launch_bounds__(256) void gemm_kernel(const bf16* __restrict__ A, const bf16* __restrict__ BT,
                                                   bf16* __restrict__ Pb, float* __restrict__ hf,
                                                   bf16* __restrict__ hb, bf16* __restrict__ shp,
                                                   float* __restrict__ Zb, const float* __restrict__ zacc,
                                                   int mode) {
    __shared__ __align__(16) char smem[16384];
    gemm_body(A, BT, Pb, hf, hb, shp, nullptr, nullptr, nullptr, Zb, zacc, mode, blockIdx.x,
              (bf16*)smem, (bf16*)(smem + 8192));
}

// fused: blocks [0,8192) run KNN (long pole first); [8192, 9216) run P-GEMM layer 0
__global__ __launch_bounds__(256) void knn_pgemm0_kernel(const bf16* __restrict__ hb,
                                                         const bf16* __restrict__ WmT0,
                                                         bf16* __restrict__ Pb,
                                                         const float* __restrict__ Zp,
                                                         const int* __restrict__ seg,
                                                         int* __restrict__ nbr) {
    __shared__ __align__(16) char smem[16384];
    if (blockIdx.x < 8192)
        knn_body(blockIdx.x, Zp, seg, nbr, (unsigned*)smem);
    else
        gemm_body(hb, WmT0, Pb, nullptr, nullptr, nullptr, nullptr, nullptr, nullptr,
                  nullptr, nullptr, 0, blockIdx.x - 8192, (bf16*)smem, (bf16*)(smem + 8192));
}

// =================== edge aggregation (bf16 P) ===================
__global__ __launch_bounds__(256) void edge_kernel(const bf16* __restrict__ Pb, const float* __restrict__ ebias,
                                                   const float* __restrict__ wz, const float* __restrict__ Zb,
                                                   const int* __restrict__ nbr, bf16* __restrict__ msum,
                                                   float* __restrict__ zacc) {
    int bid = blockIdx.x, tid = threadIdx.x;
    int b = ((bid & 7) << 10) | (bid >> 3);      // XCD-local graph for L2 reuse of Pb slice
    int c0 = 2*tid;
    int lane = tid & 63, wid = tid >> 6;
    __shared__ int srcs[18];
    __shared__ float red[18][4];
    __shared__ float term[18][3];
    if (tid < 18) srcs[tid] = nbr[b*18 + tid];
    __syncthreads();
    float2 pd  = unpack_bf2(*(const unsigned*)(Pb + (size_t)b*512 + c0));
    float2 eb0 = *(const float2*)(ebias + c0);
    float2 eb1 = *(const float2*)(ebias + 512 + c0);
    float2 w   = *(const float2*)(wz + c0);
    float ms0 = 0.0f, ms1 = 0.0f;
    float pdot[18];
    #pragma unroll
    for (int e = 0; e < 18; e++) {
        int s = srcs[e];
        float2 pv = unpack_bf2(*(const unsigned*)(Pb + (size_t)s*512 + c0));
        float ba = (e < 9) ? eb0.x : eb1.x;
        float bb = (e < 9) ? eb0.y : eb1.y;
        float m0 = silu_f(pv.x + pd.x + ba);
        float m1 = silu_f(pv.y + pd.y + bb);
        ms0 += m0; ms1 += m1;
        pdot[e] = m0*w.x + m1*w.y;
    }
    bf16x2 mp = { (bf16)ms0, (bf16)ms1 };
    *(bf16x2*)(msum + (size_t)b*512 + c0) = mp;
    #pragma unroll
    for (int e = 0; e < 18; e++) {
        float v = pdot[e];
        #pragma unroll
        for (int off = 32; off >= 1; off >>= 1) v += __shfl_xor(v, off, 64);
        if (lane == 0) red[e][wid] = v;
    }
    __syncthreads();
    if (tid < 18) {
        float dot = red[tid][0] + red[tid][1] + red[tid][2] + red[tid][3];
        float coef = tanhf(dot);
        int s = srcs[tid];
        #pragma unroll
        for (int d = 0; d < 3; d++)
            term[tid][d] = (Zb[s*3 + d] - Zb[b*3 + d]) * coef;
    }
    __syncthreads();
    if (tid < 3) {
        float s = 0.0f;
        #pragma unroll
        for (int e = 0; e < 18; e++) s += term[e][tid];
        zacc[b*3 + tid] = s;
    }
}

// =================== energy GEMM + pred_noise/loss + graph_repr in one launch ===================
__global__ __launch_bounds__(256) void egemm_fin_kernel(const bf16* __restrict__ sh, const bf16* __restrict__ W1T,
                                                        const float* __restrict__ b1, const float* __restrict__ W2,
                                                        float* __restrict__ out_e,
                                                        const float* __restrict__ hf, float* __restrict__ out_gr,
                                                        const float* __restrict__ Zb, const float* __restrict__ Zb0,
                                                        const float* __restrict__ noise,
                                                        float* __restrict__ out_pn, float* __restrict__ out_loss) {
    __shared__ __align__(16) char smem[16384];
    int bid = blockIdx.x, tid = threadIdx.x;
    if (bid < 1024) {
        gemm_body(sh, W1T, nullptr, nullptr, nullptr, nullptr, b1, W2, out_e,
                  nullptr, nullptr, 2, bid, (bf16*)smem, (bf16*)(smem + 8192));
        return;
    }
    float* red = (float*)smem;
    if (bid < 1152) {
        int u = (bid-1024)*256 + tid;
        int b = u >> 2;
        float per = 0.0f;
        #pragma unroll
        for (int d = 0; d < 3; d++) {
            float dv = Zb[b*3+d] - Zb0[b*3+d];
            out_pn[u*3+d] = dv;
            float e = dv - noise[u*3+d];
            per += e*e;
        }
        red[tid] = per; __syncthreads();
        for (int st = 128; st > 0; st >>= 1) {
            if (tid < st) red[tid] += red[tid+st];
            __syncthreads();
        }
        if (tid == 0) atomicAdd(out_loss, red[0] * (1.0f/16.0f));
        return;
    }
    int pid = bid - 1152;                // 256 partial blocks for graph_repr
    int g = pid >> 5;
    int rc = (pid >> 1) & 15;
    int ch = pid & 1;
    int c = ch*256 + tid;
    int b0 = (g << 10) + rc*64;
    float s = 0.0f;
    for (int i = 0; i < 64; i++) s += hf[(size_t)(b0+i)*512 + c];
    atomicAdd(&out_gr[g*512 + c], s);
}

// =================== unit_repr (float4) ===================
__global__ __launch_bounds__(256) void unitrepr_kernel(const int* __restrict__ Aarr, const int* __restrict__ posa,
                                                       const int* __restrict__ Barr,
                                                       const float* __restrict__ atom_emb, const float* __restrict__ pos_emb,
                                                       const float* __restrict__ block_emb,
                                                       const float* __restrict__ hf, float* __restrict__ out_ur) {
    int gid = blockIdx.x*256 + threadIdx.x;      // 32768 units x 128 threads
    int u = gid >> 7, c = (gid & 127) << 2, b = u >> 2;
    float4 va = *(const float4*)(atom_emb + (size_t)Aarr[u]*512 + c);
    float4 vp = *(const float4*)(pos_emb + (size_t)posa[u]*512 + c);
    float4 vb = *(const float4*)(block_emb + (size_t)Barr[b]*512 + c);
    float4 vh = *(const float4*)(hf + (size_t)b*512 + c);
    float4 o;
    o.x = va.x + vp.x + vb.x + vh.x;
    o.y = va.y + vp.y + vb.y + vh.y;
    o.z = va.z + vp.z + vb.z + vh.z;
    o.w = va.w + vp.w + vb.w + vh.w;
    *(float4*)(out_ur + (size_t)u*512 + c) = o;
}

extern "C" void kernel_launch(void* const* d_in, const int* in_sizes, int n_in,
                              void* d_out, int out_size, void* d_ws, size_t ws_size,
                              hipStream_t stream) {
    const float* Z         = (const float*)d_in[0];
    const int*   B         = (const int*)d_in[1];
    const int*   A         = (const int*)d_in[2];
    const int*   ap        = (const int*)d_in[3];
    const int*   seg       = (const int*)d_in[6];
    const float* noise     = (const float*)d_in[7];
    const int*   nl        = (const int*)d_in[8];
    const float* sig       = (const float*)d_in[9];
    const float* atom_emb  = (const float*)d_in[10];
    const float* pos_emb   = (const float*)d_in[11];
    const float* block_emb = (const float*)d_in[12];
    const float* edge_emb  = (const float*)d_in[13];
    const float* Wm        = (const float*)d_in[14];
    const float* We        = (const float*)d_in[15];
    const float* Wu        = (const float*)d_in[16];
    const float* wz        = (const float*)d_in[17];
    const float* W1        = (const float*)d_in[18];
    const float* b1        = (const float*)d_in[19];
    const float* W2        = (const float*)d_in[20];
    (void)in_sizes; (void)n_in; (void)d_ws; (void)ws_size; (void)out_size;

    float* out = (float*)d_out;
    const size_t o1 = 8, o2 = 98312, o3 = 16875528, o4 = 21069832, o5 = 21073928;
    float* out_e    = out;
    float* out_pn   = out + o1;
    float* out_ur   = out + o2;
    float* hf       = out + o3;   // block_repr == final h (fp32), updated in place
    float* out_gr   = out + o4;
    float* out_loss = out + o5;

    // scratch arena inside the unit_repr output region (67 MB); unit_repr written last
    char* arena = (char*)(out + o2);
    bf16*  Pb   = (bf16*)(arena);                  // 8 MB
    bf16*  msum = (bf16*)(arena + 16777216);       // 8 MB
    bf16*  sh   = (bf16*)(arena + 25165824);       // 8 MB
    bf16*  hb   = (bf16*)(arena + 33554432);       // 8 MB
    float* Zp   = (float*)(arena + 41943040);
    float* Zb0  = (float*)(arena + 42336256);
    float* Zb   = (float*)(arena + 42434560);
    float* zacc = (float*)(arena + 42532864);
    int*   nbr  = (int*)  (arena + 42631168);
    bf16*  WmT  = (bf16*) (arena + 43220992);
    bf16*  WuT  = (bf16*) (arena + 44793856);
    bf16*  W1T  = (bf16*) (arena + 46366720);
    float* ebias= (float*)(arena + 46891008);

    init_kernel<<<8192 + 1792 + 12 + 17, 256, 0, stream>>>(
        Z, noise, nl, sig, A, ap, B, atom_emb, pos_emb, block_emb,
        edge_emb, We, Wm, Wu, W1,
        Zp, Zb0, Zb, hf, hb, WmT, WuT, W1T, ebias, out_gr, out_e, out_loss);

    knn_pgemm0_kernel<<<8192 + 1024, 256, 0, stream>>>(hb, WmT, Pb, Zp, seg, nbr);

    for (int l = 0; l < 3; l++) {
        if (l > 0)
            gemm_kernel<<<1024, 256, 0, stream>>>(hb, WmT + (size_t)l*262144, Pb,
                                                  nullptr, nullptr, nullptr, nullptr, nullptr, 0);
        edge_kernel<<<8192, 256, 0, stream>>>(Pb, ebias + l*1024, wz + l*512, Zb, nbr, msum, zacc);
        gemm_kernel<<<1024, 256, 0, stream>>>(msum, WuT + (size_t)l*262144, nullptr,
                                              hf, hb, (l == 2) ? sh : nullptr, Zb, zacc, 1);
    }
    egemm_fin_kernel<<<1024 + 128 + 256, 256, 0, stream>>>(sh, W1T, b1, W2, out_e,
                                                           hf, out_gr, Zb, Zb0, noise, out_pn, out_loss);
    // unit_repr last: overwrites the scratch arena
    unitrepr_kernel<<<16384, 256, 0, stream>>>(A, ap, B, atom_emb, pos_emb, block_emb, hf, out_ur);
}

// Round 5
// 487.165 us; speedup vs baseline: 1.0884x; 1.0884x over previous
//
#include <hip/hip_runtime.h>
#include <hip/hip_bf16.h>

typedef __bf16 bf16;
typedef __bf16 bf16x2 __attribute__((ext_vector_type(2)));
typedef __bf16 bf16x8 __attribute__((ext_vector_type(8)));
typedef float floatx4 __attribute__((ext_vector_type(4)));

#define NB_ 8192
#define NU_ 32768

__device__ __forceinline__ float silu_f(float x) {
    float e = __expf(-x);
    return x * __builtin_amdgcn_rcpf(1.0f + e);
}

__device__ __forceinline__ float2 unpack_bf2(unsigned v) {
    float2 r;
    r.x = __uint_as_float(v << 16);
    r.y = __uint_as_float(v & 0xFFFF0000u);
    return r;
}

// async global -> LDS, 16B per lane; lds dest = wave-uniform base + lane*16 (HW rule)
__device__ __forceinline__ void gll16(const bf16* g, bf16* l) {
    __builtin_amdgcn_global_load_lds((const __attribute__((address_space(1))) void*)g,
                                     (__attribute__((address_space(3))) void*)l, 16, 0, 0);
}

// =================== init: setup + weight transpose + ebias + zeroing ===================
__global__ __launch_bounds__(256) void init_kernel(
    const float* __restrict__ Z, const float* __restrict__ noise,
    const int* __restrict__ nl, const float* __restrict__ sig,
    const int* __restrict__ Aarr, const int* __restrict__ posa, const int* __restrict__ Barr,
    const float* __restrict__ atom_emb, const float* __restrict__ pos_emb,
    const float* __restrict__ block_emb,
    const float* __restrict__ edge_emb, const float* __restrict__ We,
    const float* __restrict__ Wm, const float* __restrict__ Wu, const float* __restrict__ W1,
    float* __restrict__ Zp, float* __restrict__ Zb0, float* __restrict__ Zb,
    float* __restrict__ hf, bf16* __restrict__ hb,
    bf16* __restrict__ WmT, bf16* __restrict__ WuT, bf16* __restrict__ W1T,
    float* __restrict__ ebias,
    float* __restrict__ out_gr, float* __restrict__ out_e, float* __restrict__ out_loss)
{
    __shared__ float zsh[12];
    __shared__ float tile[32][33];
    int bid = blockIdx.x, tid = threadIdx.x;
    if (bid < 8192) {
        int b = bid, g = b >> 10;
        if (tid < 12) {
            float sg = sig[nl[g]];
            int idx = b*12 + tid;
            float zp = Z[idx] + noise[idx]*sg;
            Zp[idx] = zp;
            zsh[tid] = zp;
        }
        __syncthreads();
        if (tid < 3) {
            float v = 0.25f*(zsh[tid] + zsh[3+tid] + zsh[6+tid] + zsh[9+tid]);
            Zb0[b*3+tid] = v; Zb[b*3+tid] = v;
        }
        int ai[4], pi[4];
        #pragma unroll
        for (int a = 0; a < 4; a++) { ai[a] = Aarr[b*4+a]*512; pi[a] = posa[b*4+a]*512; }
        int bb = Barr[b]*512;
        int c0 = tid*2;
        float sx = 0.0f, sy = 0.0f;
        #pragma unroll
        for (int a = 0; a < 4; a++) {
            float2 va = *(const float2*)(atom_emb + ai[a] + c0);
            float2 vp = *(const float2*)(pos_emb + pi[a] + c0);
            sx += va.x + vp.x; sy += va.y + vp.y;
        }
        float2 vb = *(const float2*)(block_emb + bb + c0);
        sx = 0.25f*sx + vb.x; sy = 0.25f*sy + vb.y;
        *(float2*)(hf + (size_t)b*512 + c0) = make_float2(sx, sy);
        bf16x2 hp = { (bf16)sx, (bf16)sy };
        *(bf16x2*)(hb + (size_t)b*512 + c0) = hp;
        return;
    }
    bid -= 8192;
    if (bid < 1792) {   // 7 matrices x 256 tiles (16x16 of 32x32)
        int z = bid >> 8, rem = bid & 255;
        int bx = rem & 15, by = rem >> 4;
        int tx = tid & 31, ty = tid >> 5;     // 32 x 8
        const float* src; bf16* dst;
        if (z < 3)      { src = Wm + (size_t)z*262144;     dst = WmT + (size_t)z*262144; }
        else if (z < 6) { src = Wu + (size_t)(z-3)*262144; dst = WuT + (size_t)(z-3)*262144; }
        else            { src = W1;                        dst = W1T; }
        #pragma unroll
        for (int i = 0; i < 32; i += 8)
            tile[ty+i][tx] = src[(size_t)(by*32+ty+i)*512 + bx*32+tx];
        __syncthreads();
        #pragma unroll
        for (int i = 0; i < 32; i += 8)
            dst[(size_t)(bx*32+ty+i)*512 + by*32+tx] = (bf16)tile[tx][ty+i];
        return;
    }
    bid -= 1792;
    if (bid < 12) {
        int gid = bid*256 + tid;
        int l = gid >> 10, t = (gid >> 9) & 1, c = gid & 511;
        float s = 0.0f;
        #pragma unroll 8
        for (int e = 0; e < 64; e++)
            s += edge_emb[t*64 + e] * We[(size_t)(l*64 + e)*512 + c];
        ebias[gid] = s;
        return;
    }
    bid -= 12;
    int k = bid*256 + tid;
    if (k < 4096) out_gr[k] = 0.0f;
    else if (k < 4104) out_e[k-4096] = 0.0f;
    else if (k == 4104) out_loss[0] = 0.0f;
}

// =================== KNN: one WG per 8 dst blocks; src coords loaded once, reused 8x ===================
// u32 keys: (distbits & ~1023) | j  -> argmin via v_min_u32; unique keys -> winner by equality
__device__ void knn_body8(int kb, const float* __restrict__ Zp, const int* __restrict__ seg,
                          int* __restrict__ nbr, char* __restrict__ smem) {
    unsigned* keys = (unsigned*)smem;            // [8][1024]  32 KB
    unsigned* smk  = (unsigned*)(smem + 32768);  // [8][16][2] seg-match bit words, 1 KB
    float*    dza  = (float*)(smem + 33792);     // [96] dst atom coords
    int*      sseg = (int*)(smem + 34176);       // [8]
    int tid = threadIdx.x, w = tid >> 6, lane = tid & 63;
    int g = kb & 7, grp = kb >> 3;               // XCD-local graph
    int base = g << 10;
    int dst0 = grp << 3;
    if (tid < 96) dza[tid] = Zp[(size_t)(base + dst0)*12 + tid];
    if (tid < 8)  sseg[tid] = seg[base + dst0 + tid];
    __syncthreads();
    // load this thread's 4 src blocks once
    float sx[4][4], sy[4][4], sz[4][4]; int sj[4];
    #pragma unroll
    for (int t = 0; t < 4; t++) {
        int j = w*256 + t*64 + lane;
        const float4* p = (const float4*)(Zp + (size_t)(base + j)*12);
        float4 v0 = p[0], v1 = p[1], v2 = p[2];
        sx[t][0]=v0.x; sx[t][1]=v0.w; sx[t][2]=v1.z; sx[t][3]=v2.y;
        sy[t][0]=v0.y; sy[t][1]=v1.x; sy[t][2]=v1.w; sy[t][3]=v2.z;
        sz[t][0]=v0.z; sz[t][1]=v1.y; sz[t][2]=v2.x; sz[t][3]=v2.w;
        sj[t] = seg[base + j];
    }
    #pragma unroll
    for (int d = 0; d < 8; d++) {
        const float4* ap4 = (const float4*)(dza + d*12);
        float4 a0 = ap4[0], a1 = ap4[1], a2 = ap4[2];
        float ax[4] = {a0.x, a0.w, a1.z, a2.y};
        float ay[4] = {a0.y, a1.x, a1.w, a2.z};
        float az[4] = {a0.z, a1.y, a2.x, a2.w};
        int segd = sseg[d];
        int dl = dst0 + d;
        #pragma unroll
        for (int t = 0; t < 4; t++) {
            int j = w*256 + t*64 + lane;
            float dm = 3.0e38f;
            #pragma unroll
            for (int a = 0; a < 4; a++) {
                #pragma unroll
                for (int bq = 0; bq < 4; bq++) {
                    float dx = ax[a]-sx[t][bq], dy = ay[a]-sy[t][bq], dz = az[a]-sz[t][bq];
                    dm = fminf(dm, dx*dx + dy*dy + dz*dz);
                }
            }
            unsigned key = (__float_as_uint(dm) & 0xFFFFFC00u) | (unsigned)j;
            if (j == dl) key = 0xFFFFFFFFu;      // self: excluded from intra (and inter via seg)
            bool same = (sj[t] == segd);
            unsigned long long bal = __ballot(same);
            if (lane == 0) {
                smk[d*32 + (w*4+t)*2]     = (unsigned)bal;
                smk[d*32 + (w*4+t)*2 + 1] = (unsigned)(bal >> 32);
            }
            keys[d*1024 + j] = key;
        }
    }
    __syncthreads();
    // selection: wave w handles dsts w and w+4
    #pragma unroll
    for (int half = 0; half < 2; half++) {
        int d = w + half*4;
        int r = base + dst0 + d;
        unsigned kk[16], sm[16];
        #pragma unroll
        for (int t2 = 0; t2 < 16; t2++) {
            kk[t2] = keys[d*1024 + t2*64 + lane];
            unsigned wrd = smk[d*32 + t2*2 + (lane >> 5)];
            sm[t2] = (wrd >> (lane & 31)) & 1u;
        }
        #pragma unroll
        for (int ph = 0; ph < 2; ph++) {
            unsigned wd[16];
            #pragma unroll
            for (int t2 = 0; t2 < 16; t2++)
                wd[t2] = (ph == 0) ? (sm[t2] ? kk[t2] : 0xFFFFFFFFu)
                                   : (sm[t2] ? 0xFFFFFFFFu : kk[t2]);
            for (int it = 0; it < 9; it++) {
                unsigned bk = wd[0];
                #pragma unroll
                for (int t2 = 1; t2 < 16; t2++) bk = min(bk, wd[t2]);
                unsigned mv = bk;
                #pragma unroll
                for (int off = 32; off >= 1; off >>= 1)
                    mv = min(mv, (unsigned)__shfl_xor((int)mv, off, 64));
                if (lane == 0) nbr[r*18 + ph*9 + it] = base + (int)(mv & 1023u);
                #pragma unroll
                for (int t2 = 0; t2 < 16; t2++)
                    wd[t2] = (wd[t2] == mv) ? 0xFFFFFFFFu : wd[t2];
            }
        }
    }
}

// =================== bf16 MFMA GEMM body: 128x64 tile, BK=32, single-buffered (round-3) ===================
// grid 512 (64 M-tiles x 8 N-tiles)
// mode 0: Pb = bf16(acc)
// mode 1: hf += silu(acc); hb = bf16(hf); if shp: shp = bf16(silu(hf)); nt==0 also folds Zb += zacc/18
// mode 2: s = silu(acc + b1)·W2, wave-reduced, atomicAdd to out_e[graph]
__device__ void gemm_body(const bf16* __restrict__ A, const bf16* __restrict__ BT,
                          bf16* __restrict__ Pb, float* __restrict__ hf,
                          bf16* __restrict__ hb, bf16* __restrict__ shp,
                          const float* __restrict__ b1, const float* __restrict__ W2,
                          float* __restrict__ out_e,
                          float* __restrict__ Zb, const float* __restrict__ zacc,
                          int mode, int bid, bf16* __restrict__ sA, bf16* __restrict__ sB)
{
    int mt = bid & 63, nt = bid >> 6;
    int m0 = mt*128, n0 = nt*64;
    int tid = threadIdx.x, lane = tid & 63, w = tid >> 6;
    int wm = w & 1, wn = w >> 1;
    int lm = lane & 15, q = lane >> 4;

    // staging: physical chunk p holds logical chunk (row=p>>2, qt=(p&3)^((row>>1)&3))
    int pA0 = w*128 + lane, pA1 = pA0 + 64, pB = w*64 + lane;
    int rA0 = pA0 >> 2, qA0 = (pA0 & 3) ^ ((rA0 >> 1) & 3);
    int rA1 = pA1 >> 2, qA1 = (pA1 & 3) ^ ((rA1 >> 1) & 3);
    int rB  = pB  >> 2, qB  = (pB  & 3) ^ ((rB  >> 1) & 3);
    const bf16* gA0 = A  + (size_t)(m0 + rA0)*512 + qA0*8;
    const bf16* gA1 = A  + (size_t)(m0 + rA1)*512 + qA1*8;
    const bf16* gB  = BT + (size_t)(n0 + rB )*512 + qB*8;
    bf16* lA0 = sA + (w*128)*8;
    bf16* lA1 = sA + (w*128 + 64)*8;
    bf16* lB  = sB + (w*64)*8;

    int swq = (q ^ ((lm >> 1) & 3)) * 8;
    const bf16* pa[4]; const bf16* pb2[2];
    #pragma unroll
    for (int tm = 0; tm < 4; tm++) pa[tm] = sA + (wm*64 + tm*16 + lm)*32 + swq;
    #pragma unroll
    for (int tn = 0; tn < 2; tn++) pb2[tn] = sB + (wn*32 + tn*16 + lm)*32 + swq;

    floatx4 zv = {0.0f, 0.0f, 0.0f, 0.0f};
    floatx4 acc[4][2];
    #pragma unroll
    for (int i = 0; i < 4; i++)
        #pragma unroll
        for (int j = 0; j < 2; j++) acc[i][j] = zv;

    for (int k0 = 0; k0 < 512; k0 += 32) {
        gll16(gA0 + k0, lA0);
        gll16(gA1 + k0, lA1);
        gll16(gB  + k0, lB);
        __syncthreads();
        bf16x8 af[4], bfr[2];
        #pragma unroll
        for (int tm = 0; tm < 4; tm++) af[tm] = *(const bf16x8*)pa[tm];
        #pragma unroll
        for (int tn = 0; tn < 2; tn++) bfr[tn] = *(const bf16x8*)pb2[tn];
        #pragma unroll
        for (int tm = 0; tm < 4; tm++)
            #pragma unroll
            for (int tn = 0; tn < 2; tn++)
                acc[tm][tn] = __builtin_amdgcn_mfma_f32_16x16x32_bf16(af[tm], bfr[tn], acc[tm][tn], 0, 0, 0);
        __syncthreads();
    }

    if (mode == 2) {
        float s = 0.0f;
        #pragma unroll
        for (int tn = 0; tn < 2; tn++) {
            int col = n0 + wn*32 + tn*16 + lm;
            float bb = b1[col], ww = W2[col];
            #pragma unroll
            for (int tm = 0; tm < 4; tm++)
                #pragma unroll
                for (int rr = 0; rr < 4; rr++)
                    s += silu_f(acc[tm][tn][rr] + bb) * ww;
        }
        #pragma unroll
        for (int off = 32; off >= 1; off >>= 1) s += __shfl_xor(s, off, 64);
        if (lane == 0) atomicAdd(&out_e[m0 >> 10], s);
        return;
    }
    if (mode == 1 && nt == 0) {       // fold zb_apply: rows m0..m0+127
        int o = m0*3 + tid;
        Zb[o] += zacc[o] * (1.0f/18.0f);
        if (tid < 128) {
            int o2 = m0*3 + 256 + tid;
            Zb[o2] += zacc[o2] * (1.0f/18.0f);
        }
    }
    #pragma unroll
    for (int tm = 0; tm < 4; tm++) {
        #pragma unroll
        for (int tn = 0; tn < 2; tn++) {
            #pragma unroll
            for (int rr = 0; rr < 4; rr++) {
                int r2 = m0 + wm*64 + tm*16 + q*4 + rr;
                int c2 = n0 + wn*32 + tn*16 + lm;
                size_t o = (size_t)r2*512 + c2;
                float v = acc[tm][tn][rr];
                if (mode == 0) {
                    Pb[o] = (bf16)v;
                } else {
                    float nh = hf[o] + silu_f(v);
                    hf[o] = nh;
                    hb[o] = (bf16)nh;
                    if (shp) shp[o] = (bf16)silu_f(nh);
                }
            }
        }
    }
}

__global__ __launch_bounds__(256) void gemm_kernel(const bf16* __restrict__ A, const bf16* __restrict__ BT,
                                                   bf16* __restrict__ Pb, float* __restrict__ hf,
                                                   bf16* __restrict__ hb, bf16* __restrict__ shp,
                                                   float* __restrict__ Zb, const float* __restrict__ zacc,
                                                   int mode) {
    __shared__ __align__(16) char smem[12288];
    gemm_body(A, BT, Pb, hf, hb, shp, nullptr, nullptr, nullptr, Zb, zacc, mode, blockIdx.x,
              (bf16*)smem, (bf16*)(smem + 8192));
}

// fused: blocks [0,1024) run KNN (8 dsts each); [1024, 1536) run P-GEMM layer 0
__global__ __launch_bounds__(256) void knn_pgemm0_kernel(const bf16* __restrict__ hb,
                                                         const bf16* __restrict__ WmT0,
                                                         bf16* __restrict__ Pb,
                                                         const float* __restrict__ Zp,
                                                         const int* __restrict__ seg,
                                                         int* __restrict__ nbr) {
    __shared__ __align__(16) char smem[34240];
    if (blockIdx.x < 1024)
        knn_body8(blockIdx.x, Zp, seg, nbr, smem);
    else
        gemm_body(hb, WmT0, Pb, nullptr, nullptr, nullptr, nullptr, nullptr, nullptr,
                  nullptr, nullptr, 0, blockIdx.x - 1024, (bf16*)smem, (bf16*)(smem + 8192));
}

// =================== edge aggregation (bf16 P) ===================
__global__ __launch_bounds__(256) void edge_kernel(const bf16* __restrict__ Pb, const float* __restrict__ ebias,
                                                   const float* __restrict__ wz, const float* __restrict__ Zb,
                                                   const int* __restrict__ nbr, bf16* __restrict__ msum,
                                                   float* __restrict__ zacc) {
    int bid = blockIdx.x, tid = threadIdx.x;
    int b = ((bid & 7) << 10) | (bid >> 3);      // XCD-local graph for L2 reuse of Pb slice
    int c0 = 2*tid;
    int lane = tid & 63, wid = tid >> 6;
    __shared__ int srcs[18];
    __shared__ float red[18][4];
    __shared__ float term[18][3];
    if (tid < 18) srcs[tid] = nbr[b*18 + tid];
    __syncthreads();
    float2 pd  = unpack_bf2(*(const unsigned*)(Pb + (size_t)b*512 + c0));
    float2 eb0 = *(const float2*)(ebias + c0);
    float2 eb1 = *(const float2*)(ebias + 512 + c0);
    float2 w   = *(const float2*)(wz + c0);
    float ms0 = 0.0f, ms1 = 0.0f;
    float pdot[18];
    #pragma unroll
    for (int e = 0; e < 18; e++) {
        int s = srcs[e];
        float2 pv = unpack_bf2(*(const unsigned*)(Pb + (size_t)s*512 + c0));
        float ba = (e < 9) ? eb0.x : eb1.x;
        float bb = (e < 9) ? eb0.y : eb1.y;
        float m0 = silu_f(pv.x + pd.x + ba);
        float m1 = silu_f(pv.y + pd.y + bb);
        ms0 += m0; ms1 += m1;
        pdot[e] = m0*w.x + m1*w.y;
    }
    bf16x2 mp = { (bf16)ms0, (bf16)ms1 };
    *(bf16x2*)(msum + (size_t)b*512 + c0) = mp;
    #pragma unroll
    for (int e = 0; e < 18; e++) {
        float v = pdot[e];
        #pragma unroll
        for (int off = 32; off >= 1; off >>= 1) v += __shfl_xor(v, off, 64);
        if (lane == 0) red[e][wid] = v;
    }
    __syncthreads();
    if (tid < 18) {
        float dot = red[tid][0] + red[tid][1] + red[tid][2] + red[tid][3];
        float coef = tanhf(dot);
        int s = srcs[tid];
        #pragma unroll
        for (int d = 0; d < 3; d++)
            term[tid][d] = (Zb[s*3 + d] - Zb[b*3 + d]) * coef;
    }
    __syncthreads();
    if (tid < 3) {
        float s = 0.0f;
        #pragma unroll
        for (int e = 0; e < 18; e++) s += term[e][tid];
        zacc[b*3 + tid] = s;
    }
}

// =================== energy GEMM + pred_noise/loss + graph_repr in one launch ===================
__global__ __launch_bounds__(256) void egemm_fin_kernel(const bf16* __restrict__ sh, const bf16* __restrict__ W1T,
                                                        const float* __restrict__ b1, const float* __restrict__ W2,
                                                        float* __restrict__ out_e,
                                                        const float* __restrict__ hf, float* __restrict__ out_gr,
                                                        const float* __restrict__ Zb, const float* __restrict__ Zb0,
                                                        const float* __restrict__ noise,
                                                        float* __restrict__ out_pn, float* __restrict__ out_loss) {
    __shared__ __align__(16) char smem[12288];
    int bid = blockIdx.x, tid = threadIdx.x;
    if (bid < 512) {
        gemm_body(sh, W1T, nullptr, nullptr, nullptr, nullptr, b1, W2, out_e,
                  nullptr, nullptr, 2, bid, (bf16*)smem, (bf16*)(smem + 8192));
        return;
    }
    float* red = (float*)smem;
    if (bid < 640) {
        int u = (bid-512)*256 + tid;
        int b = u >> 2;
        float per = 0.0f;
        #pragma unroll
        for (int d = 0; d < 3; d++) {
            float dv = Zb[b*3+d] - Zb0[b*3+d];
            out_pn[u*3+d] = dv;
            float e = dv - noise[u*3+d];
            per += e*e;
        }
        red[tid] = per; __syncthreads();
        for (int st = 128; st > 0; st >>= 1) {
            if (tid < st) red[tid] += red[tid+st];
            __syncthreads();
        }
        if (tid == 0) atomicAdd(out_loss, red[0] * (1.0f/16.0f));
        return;
    }
    int pid = bid - 640;                // 256 partial blocks for graph_repr
    int g = pid >> 5;
    int rc = (pid >> 1) & 15;
    int ch = pid & 1;
    int c = ch*256 + tid;
    int b0 = (g << 10) + rc*64;
    float s = 0.0f;
    for (int i = 0; i < 64; i++) s += hf[(size_t)(b0+i)*512 + c];
    atomicAdd(&out_gr[g*512 + c], s);
}

// =================== unit_repr (float4) ===================
__global__ __launch_bounds__(256) void unitrepr_kernel(const int* __restrict__ Aarr, const int* __restrict__ posa,
                                                       const int* __restrict__ Barr,
                                                       const float* __restrict__ atom_emb, const float* __restrict__ pos_emb,
                                                       const float* __restrict__ block_emb,
                                                       const float* __restrict__ hf, float* __restrict__ out_ur) {
    int gid = blockIdx.x*256 + threadIdx.x;      // 32768 units x 128 threads
    int u = gid >> 7, c = (gid & 127) << 2, b = u >> 2;
    float4 va = *(const float4*)(atom_emb + (size_t)Aarr[u]*512 + c);
    float4 vp = *(const float4*)(pos_emb + (size_t)posa[u]*512 + c);
    float4 vb = *(const float4*)(block_emb + (size_t)Barr[b]*512 + c);
    float4 vh = *(const float4*)(hf + (size_t)b*512 + c);
    float4 o;
    o.x = va.x + vp.x + vb.x + vh.x;
    o.y = va.y + vp.y + vb.y + vh.y;
    o.z = va.z + vp.z + vb.z + vh.z;
    o.w = va.w + vp.w + vb.w + vh.w;
    *(float4*)(out_ur + (size_t)u*512 + c) = o;
}

extern "C" void kernel_launch(void* const* d_in, const int* in_sizes, int n_in,
                              void* d_out, int out_size, void* d_ws, size_t ws_size,
                              hipStream_t stream) {
    const float* Z         = (const float*)d_in[0];
    const int*   B         = (const int*)d_in[1];
    const int*   A         = (const int*)d_in[2];
    const int*   ap        = (const int*)d_in[3];
    const int*   seg       = (const int*)d_in[6];
    const float* noise     = (const float*)d_in[7];
    const int*   nl        = (const int*)d_in[8];
    const float* sig       = (const float*)d_in[9];
    const float* atom_emb  = (const float*)d_in[10];
    const float* pos_emb   = (const float*)d_in[11];
    const float* block_emb = (const float*)d_in[12];
    const float* edge_emb  = (const float*)d_in[13];
    const float* Wm        = (const float*)d_in[14];
    const float* We        = (const float*)d_in[15];
    const float* Wu        = (const float*)d_in[16];
    const float* wz        = (const float*)d_in[17];
    const float* W1        = (const float*)d_in[18];
    const float* b1        = (const float*)d_in[19];
    const float* W2        = (const float*)d_in[20];
    (void)in_sizes; (void)n_in; (void)d_ws; (void)ws_size; (void)out_size;

    float* out = (float*)d_out;
    const size_t o1 = 8, o2 = 98312, o3 = 16875528, o4 = 21069832, o5 = 21073928;
    float* out_e    = out;
    float* out_pn   = out + o1;
    float* out_ur   = out + o2;
    float* hf       = out + o3;   // block_repr == final h (fp32), updated in place
    float* out_gr   = out + o4;
    float* out_loss = out + o5;

    // scratch arena inside the unit_repr output region (67 MB); unit_repr written last
    char* arena = (char*)(out + o2);
    bf16*  Pb   = (bf16*)(arena);                  // 8 MB
    bf16*  msum = (bf16*)(arena + 16777216);       // 8 MB
    bf16*  sh   = (bf16*)(arena + 25165824);       // 8 MB
    bf16*  hb   = (bf16*)(arena + 33554432);       // 8 MB
    float* Zp   = (float*)(arena + 41943040);
    float* Zb0  = (float*)(arena + 42336256);
    float* Zb   = (float*)(arena + 42434560);
    float* zacc = (float*)(arena + 42532864);
    int*   nbr  = (int*)  (arena + 42631168);
    bf16*  WmT  = (bf16*) (arena + 43220992);
    bf16*  WuT  = (bf16*) (arena + 44793856);
    bf16*  W1T  = (bf16*) (arena + 46366720);
    float* ebias= (float*)(arena + 46891008);

    init_kernel<<<8192 + 1792 + 12 + 17, 256, 0, stream>>>(
        Z, noise, nl, sig, A, ap, B, atom_emb, pos_emb, block_emb,
        edge_emb, We, Wm, Wu, W1,
        Zp, Zb0, Zb, hf, hb, WmT, WuT, W1T, ebias, out_gr, out_e, out_loss);

    knn_pgemm0_kernel<<<1024 + 512, 256, 0, stream>>>(hb, WmT, Pb, Zp, seg, nbr);

    for (int l = 0; l < 3; l++) {
        if (l > 0)
            gemm_kernel<<<512, 256, 0, stream>>>(hb, WmT + (size_t)l*262144, Pb,
                                                 nullptr, nullptr, nullptr, nullptr, nullptr, 0);
        edge_kernel<<<8192, 256, 0, stream>>>(Pb, ebias + l*1024, wz + l*512, Zb, nbr, msum, zacc);
        gemm_kernel<<<512, 256, 0, stream>>>(msum, WuT + (size_t)l*262144, nullptr,
                                             hf, hb, (l == 2) ? sh : nullptr, Zb, zacc, 1);
    }
    egemm_fin_kernel<<<512 + 128 + 256, 256, 0, stream>>>(sh, W1T, b1, W2, out_e,
                                                          hf, out_gr, Zb, Zb0, noise, out_pn, out_loss);
    // unit_repr last: overwrites the scratch arena
    unitrepr_kernel<<<16384, 256, 0, stream>>>(A, ap, B, atom_emb, pos_emb, block_emb, hf, out_ur);
}